// Round 1
// baseline (251.050 us; speedup 1.0000x reference)
//
#include <hip/hip_runtime.h>
#include <math.h>

#define N_NODES 10000
#define N_EDGES 640000
#define C 128          // IN_C == OUT_C
#define GM 32          // nodes per GEMM block

// ---------------- degree counting ----------------
__global__ void zero_deg_kernel(int* __restrict__ deg) {
    int i = blockIdx.x * blockDim.x + threadIdx.x;
    if (i < N_NODES) deg[i] = 0;
}

__global__ void count_deg_kernel(const int* __restrict__ col, int* __restrict__ deg) {
    int e = blockIdx.x * blockDim.x + threadIdx.x;
    if (e < N_EDGES) atomicAdd(&deg[col[e]], 1);
}

// ---------------- prefix scan + dinv ----------------
// Single block of 1024 threads, 10 elements per thread (10240 >= 10000).
__global__ __launch_bounds__(1024) void scan_kernel(const int* __restrict__ deg,
                                                    int* __restrict__ row_off,
                                                    int* __restrict__ cursor,
                                                    float* __restrict__ dinv) {
    __shared__ int sm[1024];
    const int PER = 10;
    int tid = threadIdx.x;
    int base = tid * PER;
    int local[PER];
    int s = 0;
#pragma unroll
    for (int k = 0; k < PER; k++) {
        int i = base + k;
        int v = (i < N_NODES) ? deg[i] : 0;
        local[k] = s;       // exclusive prefix within thread
        s += v;
    }
    sm[tid] = s;
    __syncthreads();
    // Hillis-Steele inclusive scan over 1024 thread sums
    for (int off = 1; off < 1024; off <<= 1) {
        int t = (tid >= off) ? sm[tid - off] : 0;
        __syncthreads();
        sm[tid] += t;
        __syncthreads();
    }
    int excl_base = sm[tid] - s;
#pragma unroll
    for (int k = 0; k < PER; k++) {
        int i = base + k;
        if (i < N_NODES) {
            int e = excl_base + local[k];
            row_off[i] = e;
            cursor[i]  = e;
        }
    }
    if (tid == 1023) row_off[N_NODES] = sm[1023];   // == N_EDGES
    // dinv = (deg+1)^-0.5  (self loop included)
    for (int i = tid; i < N_NODES; i += 1024) {
        dinv[i] = rsqrtf((float)(deg[i] + 1));
    }
}

// ---------------- counting-sort fill of CSR ----------------
__global__ void fill_csr_kernel(const int* __restrict__ row, const int* __restrict__ col,
                                int* __restrict__ cursor, int* __restrict__ csr_src) {
    int e = blockIdx.x * blockDim.x + threadIdx.x;
    if (e < N_EDGES) {
        int c = col[e];
        int pos = atomicAdd(&cursor[c], 1);
        csr_src[pos] = row[e];
    }
}

// ---------------- h = x @ W^T (fp32 vector ALU) ----------------
// Block = 256 threads: (128 channels) x (2 node groups). Each thread computes
// 16 nodes for one output channel. x tile staged in LDS (broadcast reads,
// conflict-free); W rows streamed from global (64 KB, L2-resident).
__global__ __launch_bounds__(256) void gemm_kernel(const float* __restrict__ x,
                                                   const float* __restrict__ W,
                                                   float* __restrict__ h) {
    __shared__ float4 xs[GM * 32];   // 32 nodes x 128 floats = 16 KB
    int block0 = blockIdx.x * GM;
    int tid = threadIdx.x;
    const float4* xv = (const float4*)x + (size_t)block0 * 32;
    int total4 = N_NODES * 32;
    for (int i = tid; i < GM * 32; i += 256) {
        int g = block0 * 32 + i;
        xs[i] = (g < total4) ? xv[i] : make_float4(0.f, 0.f, 0.f, 0.f);
    }
    __syncthreads();

    int ch = tid & 127;   // output channel
    int ty = tid >> 7;    // 0..1
    const float4* Wv = (const float4*)(W + ch * C);
    float acc[GM / 2];
#pragma unroll
    for (int n = 0; n < GM / 2; n++) acc[n] = 0.f;

    for (int kk = 0; kk < 32; kk++) {
        float4 w4 = Wv[kk];
#pragma unroll
        for (int n = 0; n < GM / 2; n++) {
            float4 x4 = xs[(2 * n + ty) * 32 + kk];
            acc[n] += w4.x * x4.x + w4.y * x4.y + w4.z * x4.z + w4.w * x4.w;
        }
    }
#pragma unroll
    for (int n = 0; n < GM / 2; n++) {
        int node = block0 + 2 * n + ty;
        if (node < N_NODES) h[(size_t)node * C + ch] = acc[n];
    }
}

// ---------------- gather: one wave per destination node ----------------
__global__ __launch_bounds__(256) void gather_kernel(const float* __restrict__ h,
                                                     const float* __restrict__ dinv,
                                                     const int* __restrict__ row_off,
                                                     const int* __restrict__ csr_src,
                                                     const float* __restrict__ b,
                                                     float* __restrict__ out) {
    int wave = threadIdx.x >> 6;
    int lane = threadIdx.x & 63;
    int node = blockIdx.x * 4 + wave;
    if (node >= N_NODES) return;

    int beg = row_off[node];
    int end = row_off[node + 1];
    const float2* h2 = (const float2*)h;
    float2 acc = make_float2(0.f, 0.f);

    for (int j = beg; j < end; j++) {
        int r = csr_src[j];          // broadcast (same addr across lanes)
        float w = dinv[r];           // broadcast
        float2 hv = h2[(size_t)r * 64 + lane];   // coalesced 512B
        acc.x += w * hv.x;
        acc.y += w * hv.y;
    }
    float dc = dinv[node];
    float2 hs = h2[(size_t)node * 64 + lane];
    // out = dinv[c] * (sum_r dinv[r] h[r] + dinv[c] h[c]) + b
    acc.x = dc * (acc.x + dc * hs.x);
    acc.y = dc * (acc.y + dc * hs.y);
    float2 bb = ((const float2*)b)[lane];
    acc.x += bb.x;
    acc.y += bb.y;
    ((float2*)out)[(size_t)node * 64 + lane] = acc;
}

extern "C" void kernel_launch(void* const* d_in, const int* in_sizes, int n_in,
                              void* d_out, int out_size, void* d_ws, size_t ws_size,
                              hipStream_t stream) {
    const float* x  = (const float*)d_in[0];
    const float* W  = (const float*)d_in[1];
    const float* b  = (const float*)d_in[2];
    const int*   ei = (const int*)d_in[3];
    const int* row = ei;             // ei[0]
    const int* col = ei + N_EDGES;   // ei[1]

    char* ws = (char*)d_ws;
    // ws layout (bytes):
    float* h        = (float*)(ws + 0);          // 5,120,000 B
    int*   deg      = (int*)  (ws + 5120000);    //    40,000 B
    float* dinv     = (float*)(ws + 5160192);    //    40,000 B
    int*   row_off  = (int*)  (ws + 5200384);    //    40,004 B
    int*   cursor   = (int*)  (ws + 5240576);    //    40,000 B
    int*   csr_src  = (int*)  (ws + 5280768);    // 2,560,000 B  (total ~7.85 MB)
    float* out      = (float*)d_out;

    hipLaunchKernelGGL(zero_deg_kernel, dim3((N_NODES + 255) / 256), dim3(256), 0, stream, deg);
    hipLaunchKernelGGL(count_deg_kernel, dim3(N_EDGES / 256), dim3(256), 0, stream, col, deg);
    hipLaunchKernelGGL(scan_kernel, dim3(1), dim3(1024), 0, stream, deg, row_off, cursor, dinv);
    hipLaunchKernelGGL(fill_csr_kernel, dim3(N_EDGES / 256), dim3(256), 0, stream, row, col, cursor, csr_src);
    hipLaunchKernelGGL(gemm_kernel, dim3((N_NODES + GM - 1) / GM), dim3(256), 0, stream, x, W, h);
    hipLaunchKernelGGL(gather_kernel, dim3((N_NODES + 3) / 4), dim3(256), 0, stream, h, dinv, row_off, csr_src, b, out);
}

// Round 2
// 207.238 us; speedup vs baseline: 1.2114x; 1.2114x over previous
//
#include <hip/hip_runtime.h>
#include <math.h>

#define N_NODES 10000
#define N_EDGES 640000
#define C 128          // IN_C == OUT_C
#define GM 32          // nodes per GEMM block

// ---------------- degree counting ----------------
__global__ void zero_deg_kernel(int* __restrict__ deg) {
    int i = blockIdx.x * blockDim.x + threadIdx.x;
    if (i < N_NODES) deg[i] = 0;
}

// 4 edges per thread via int4
__global__ void count_deg_kernel(const int* __restrict__ col, int* __restrict__ deg) {
    int i = blockIdx.x * blockDim.x + threadIdx.x;   // i < N_EDGES/4
    if (i < N_EDGES / 4) {
        int4 c4 = ((const int4*)col)[i];
        atomicAdd(&deg[c4.x], 1);
        atomicAdd(&deg[c4.y], 1);
        atomicAdd(&deg[c4.z], 1);
        atomicAdd(&deg[c4.w], 1);
    }
}

// ---------------- prefix scan + dinv ----------------
__global__ __launch_bounds__(1024) void scan_kernel(const int* __restrict__ deg,
                                                    int* __restrict__ row_off,
                                                    int* __restrict__ cursor,
                                                    float* __restrict__ dinv) {
    __shared__ int sm[1024];
    const int PER = 10;
    int tid = threadIdx.x;
    int base = tid * PER;
    int local[PER];
    int s = 0;
#pragma unroll
    for (int k = 0; k < PER; k++) {
        int i = base + k;
        int v = (i < N_NODES) ? deg[i] : 0;
        local[k] = s;
        s += v;
    }
    sm[tid] = s;
    __syncthreads();
    for (int off = 1; off < 1024; off <<= 1) {
        int t = (tid >= off) ? sm[tid - off] : 0;
        __syncthreads();
        sm[tid] += t;
        __syncthreads();
    }
    int excl_base = sm[tid] - s;
#pragma unroll
    for (int k = 0; k < PER; k++) {
        int i = base + k;
        if (i < N_NODES) {
            int e = excl_base + local[k];
            row_off[i] = e;
            cursor[i]  = e;
        }
    }
    if (tid == 1023) row_off[N_NODES] = sm[1023];
    for (int i = tid; i < N_NODES; i += 1024) {
        dinv[i] = rsqrtf((float)(deg[i] + 1));
    }
}

// ---------------- counting-sort fill of CSR ----------------
__global__ void fill_csr_kernel(const int* __restrict__ row, const int* __restrict__ col,
                                int* __restrict__ cursor, int* __restrict__ csr_src) {
    int i = blockIdx.x * blockDim.x + threadIdx.x;
    if (i < N_EDGES / 4) {
        int4 r4 = ((const int4*)row)[i];
        int4 c4 = ((const int4*)col)[i];
        csr_src[atomicAdd(&cursor[c4.x], 1)] = r4.x;
        csr_src[atomicAdd(&cursor[c4.y], 1)] = r4.y;
        csr_src[atomicAdd(&cursor[c4.z], 1)] = r4.z;
        csr_src[atomicAdd(&cursor[c4.w], 1)] = r4.w;
    }
}

// ---------------- h' = dinv * (x @ W^T) ----------------
__global__ __launch_bounds__(256) void gemm_kernel(const float* __restrict__ x,
                                                   const float* __restrict__ W,
                                                   const float* __restrict__ dinv,
                                                   float* __restrict__ h) {
    __shared__ float4 xs[GM * 32];   // 32 nodes x 128 floats = 16 KB
    int block0 = blockIdx.x * GM;
    int tid = threadIdx.x;
    const float4* xv = (const float4*)x + (size_t)block0 * 32;
    int total4 = N_NODES * 32;
    for (int i = tid; i < GM * 32; i += 256) {
        int g = block0 * 32 + i;
        xs[i] = (g < total4) ? xv[i] : make_float4(0.f, 0.f, 0.f, 0.f);
    }
    __syncthreads();

    int ch = tid & 127;
    int ty = tid >> 7;
    const float4* Wv = (const float4*)(W + ch * C);
    float acc[GM / 2];
#pragma unroll
    for (int n = 0; n < GM / 2; n++) acc[n] = 0.f;

    for (int kk = 0; kk < 32; kk++) {
        float4 w4 = Wv[kk];
#pragma unroll
        for (int n = 0; n < GM / 2; n++) {
            float4 x4 = xs[(2 * n + ty) * 32 + kk];
            acc[n] += w4.x * x4.x + w4.y * x4.y + w4.z * x4.z + w4.w * x4.w;
        }
    }
#pragma unroll
    for (int n = 0; n < GM / 2; n++) {
        int node = block0 + 2 * n + ty;
        if (node < N_NODES) h[(size_t)node * C + ch] = acc[n] * dinv[node];
    }
}

// ---------------- gather: one wave per destination node ----------------
// h is pre-scaled by dinv, so the edge loop is a pure sum of h'[r].
// Edge indices loaded coalesced (64/wave) and broadcast via shfl; inner loop
// unrolled x8 -> 8 independent 512B loads in flight.
__global__ __launch_bounds__(256) void gather_kernel(const float* __restrict__ h,
                                                     const float* __restrict__ dinv,
                                                     const int* __restrict__ row_off,
                                                     const int* __restrict__ csr_src,
                                                     const float* __restrict__ b,
                                                     float* __restrict__ out) {
    int wave = threadIdx.x >> 6;
    int lane = threadIdx.x & 63;
    int node = blockIdx.x * 4 + wave;
    if (node >= N_NODES) return;

    int beg = row_off[node];
    int end = row_off[node + 1];
    const float2* h2 = (const float2*)h;
    float ax = 0.f, ay = 0.f;

    for (int j0 = beg; j0 < end; j0 += 64) {
        int n = end - j0;
        if (n > 64) n = 64;
        int idx = (lane < n) ? csr_src[j0 + lane] : 0;   // coalesced
        int k = 0;
        for (; k + 8 <= n; k += 8) {
            int r0 = __shfl(idx, k + 0);
            int r1 = __shfl(idx, k + 1);
            int r2 = __shfl(idx, k + 2);
            int r3 = __shfl(idx, k + 3);
            int r4 = __shfl(idx, k + 4);
            int r5 = __shfl(idx, k + 5);
            int r6 = __shfl(idx, k + 6);
            int r7 = __shfl(idx, k + 7);
            float2 v0 = h2[(size_t)r0 * 64 + lane];
            float2 v1 = h2[(size_t)r1 * 64 + lane];
            float2 v2 = h2[(size_t)r2 * 64 + lane];
            float2 v3 = h2[(size_t)r3 * 64 + lane];
            float2 v4 = h2[(size_t)r4 * 64 + lane];
            float2 v5 = h2[(size_t)r5 * 64 + lane];
            float2 v6 = h2[(size_t)r6 * 64 + lane];
            float2 v7 = h2[(size_t)r7 * 64 + lane];
            ax += v0.x + v1.x + v2.x + v3.x + v4.x + v5.x + v6.x + v7.x;
            ay += v0.y + v1.y + v2.y + v3.y + v4.y + v5.y + v6.y + v7.y;
        }
        for (; k < n; k++) {
            int r = __shfl(idx, k);
            float2 v = h2[(size_t)r * 64 + lane];
            ax += v.x;
            ay += v.y;
        }
    }
    float dc = dinv[node];
    float2 hs = h2[(size_t)node * 64 + lane];   // h'[c] = dinv[c]*h[c]
    ax = dc * (ax + hs.x);
    ay = dc * (ay + hs.y);
    float2 bb = ((const float2*)b)[lane];
    float2 res = make_float2(ax + bb.x, ay + bb.y);
    ((float2*)out)[(size_t)node * 64 + lane] = res;
}

extern "C" void kernel_launch(void* const* d_in, const int* in_sizes, int n_in,
                              void* d_out, int out_size, void* d_ws, size_t ws_size,
                              hipStream_t stream) {
    const float* x  = (const float*)d_in[0];
    const float* W  = (const float*)d_in[1];
    const float* b  = (const float*)d_in[2];
    const int*   ei = (const int*)d_in[3];
    const int* row = ei;             // ei[0]
    const int* col = ei + N_EDGES;   // ei[1]

    char* ws = (char*)d_ws;
    float* h        = (float*)(ws + 0);          // 5,120,000 B
    int*   deg      = (int*)  (ws + 5120000);
    float* dinv     = (float*)(ws + 5160192);
    int*   row_off  = (int*)  (ws + 5200384);
    int*   cursor   = (int*)  (ws + 5240576);
    int*   csr_src  = (int*)  (ws + 5280768);    // 2,560,000 B
    float* out      = (float*)d_out;

    hipLaunchKernelGGL(zero_deg_kernel, dim3((N_NODES + 255) / 256), dim3(256), 0, stream, deg);
    hipLaunchKernelGGL(count_deg_kernel, dim3(N_EDGES / 4 / 256), dim3(256), 0, stream, col, deg);
    hipLaunchKernelGGL(scan_kernel, dim3(1), dim3(1024), 0, stream, deg, row_off, cursor, dinv);
    hipLaunchKernelGGL(fill_csr_kernel, dim3(N_EDGES / 4 / 256), dim3(256), 0, stream, row, col, cursor, csr_src);
    hipLaunchKernelGGL(gemm_kernel, dim3((N_NODES + GM - 1) / GM), dim3(256), 0, stream, x, W, dinv, h);
    hipLaunchKernelGGL(gather_kernel, dim3((N_NODES + 3) / 4), dim3(256), 0, stream, h, dinv, row_off, csr_src, b, out);
}

// Round 3
// 197.061 us; speedup vs baseline: 1.2740x; 1.0516x over previous
//
#include <hip/hip_runtime.h>
#include <hip/hip_bf16.h>
#include <math.h>

#define N_NODES 10000
#define N_EDGES 640000
#define C 128          // IN_C == OUT_C
#define GM 32          // nodes per GEMM block

// ---------------- degree counting ----------------
__global__ void zero_deg_kernel(int* __restrict__ deg) {
    int i = blockIdx.x * blockDim.x + threadIdx.x;
    if (i < N_NODES) deg[i] = 0;
}

__global__ void count_deg_kernel(const int* __restrict__ col, int* __restrict__ deg) {
    int i = blockIdx.x * blockDim.x + threadIdx.x;   // i < N_EDGES/4
    if (i < N_EDGES / 4) {
        int4 c4 = ((const int4*)col)[i];
        atomicAdd(&deg[c4.x], 1);
        atomicAdd(&deg[c4.y], 1);
        atomicAdd(&deg[c4.z], 1);
        atomicAdd(&deg[c4.w], 1);
    }
}

// ---------------- prefix scan + dinv ----------------
__global__ __launch_bounds__(1024) void scan_kernel(const int* __restrict__ deg,
                                                    int* __restrict__ row_off,
                                                    int* __restrict__ cursor,
                                                    float* __restrict__ dinv) {
    __shared__ int sm[1024];
    const int PER = 10;
    int tid = threadIdx.x;
    int base = tid * PER;
    int local[PER];
    int s = 0;
#pragma unroll
    for (int k = 0; k < PER; k++) {
        int i = base + k;
        int v = (i < N_NODES) ? deg[i] : 0;
        local[k] = s;
        s += v;
    }
    sm[tid] = s;
    __syncthreads();
    for (int off = 1; off < 1024; off <<= 1) {
        int t = (tid >= off) ? sm[tid - off] : 0;
        __syncthreads();
        sm[tid] += t;
        __syncthreads();
    }
    int excl_base = sm[tid] - s;
#pragma unroll
    for (int k = 0; k < PER; k++) {
        int i = base + k;
        if (i < N_NODES) {
            int e = excl_base + local[k];
            row_off[i] = e;
            cursor[i]  = e;
        }
    }
    if (tid == 1023) row_off[N_NODES] = sm[1023];
    for (int i = tid; i < N_NODES; i += 1024) {
        dinv[i] = rsqrtf((float)(deg[i] + 1));
    }
}

// ---------------- counting-sort fill of CSR ----------------
__global__ void fill_csr_kernel(const int* __restrict__ row, const int* __restrict__ col,
                                int* __restrict__ cursor, int* __restrict__ csr_src) {
    int i = blockIdx.x * blockDim.x + threadIdx.x;
    if (i < N_EDGES / 4) {
        int4 r4 = ((const int4*)row)[i];
        int4 c4 = ((const int4*)col)[i];
        csr_src[atomicAdd(&cursor[c4.x], 1)] = r4.x;
        csr_src[atomicAdd(&cursor[c4.y], 1)] = r4.y;
        csr_src[atomicAdd(&cursor[c4.z], 1)] = r4.z;
        csr_src[atomicAdd(&cursor[c4.w], 1)] = r4.w;
    }
}

// ---------------- h' = bf16(dinv * (x @ W^T)) ----------------
// fp32 compute on the vector ALU; epilogue scales by dinv[node] and rounds
// to bf16 so the gather's working set (2.56 MB) fits in every XCD's 4 MiB L2.
__global__ __launch_bounds__(256) void gemm_kernel(const float* __restrict__ x,
                                                   const float* __restrict__ W,
                                                   const float* __restrict__ dinv,
                                                   __hip_bfloat16* __restrict__ h) {
    __shared__ float4 xs[GM * 32];   // 32 nodes x 128 floats = 16 KB
    int block0 = blockIdx.x * GM;
    int tid = threadIdx.x;
    const float4* xv = (const float4*)x + (size_t)block0 * 32;
    int total4 = N_NODES * 32;
    for (int i = tid; i < GM * 32; i += 256) {
        int g = block0 * 32 + i;
        xs[i] = (g < total4) ? xv[i] : make_float4(0.f, 0.f, 0.f, 0.f);
    }
    __syncthreads();

    int ch = tid & 127;
    int ty = tid >> 7;
    const float4* Wv = (const float4*)(W + ch * C);
    float acc[GM / 2];
#pragma unroll
    for (int n = 0; n < GM / 2; n++) acc[n] = 0.f;

    for (int kk = 0; kk < 32; kk++) {
        float4 w4 = Wv[kk];
#pragma unroll
        for (int n = 0; n < GM / 2; n++) {
            float4 x4 = xs[(2 * n + ty) * 32 + kk];
            acc[n] += w4.x * x4.x + w4.y * x4.y + w4.z * x4.z + w4.w * x4.w;
        }
    }
#pragma unroll
    for (int n = 0; n < GM / 2; n++) {
        int node = block0 + 2 * n + ty;
        if (node < N_NODES)
            h[(size_t)node * C + ch] = __float2bfloat16(acc[n] * dinv[node]);
    }
}

// ---------------- gather: one wave per destination node ----------------
// h' is bf16 and pre-scaled by dinv. Lane loads one dword = 2 bf16 channels
// per edge (coalesced 256B/wave); indices loaded coalesced + shfl-broadcast;
// x8 unroll keeps 8 independent loads in flight.
__device__ __forceinline__ float bf_lo(unsigned int v) {
    return __uint_as_float(v << 16);
}
__device__ __forceinline__ float bf_hi(unsigned int v) {
    return __uint_as_float(v & 0xffff0000u);
}

__global__ __launch_bounds__(256) void gather_kernel(const unsigned int* __restrict__ h2,
                                                     const float* __restrict__ dinv,
                                                     const int* __restrict__ row_off,
                                                     const int* __restrict__ csr_src,
                                                     const float* __restrict__ b,
                                                     float* __restrict__ out) {
    int wave = threadIdx.x >> 6;
    int lane = threadIdx.x & 63;
    int node = blockIdx.x * 4 + wave;
    if (node >= N_NODES) return;

    int beg = row_off[node];
    int end = row_off[node + 1];
    float ax = 0.f, ay = 0.f;

    for (int j0 = beg; j0 < end; j0 += 64) {
        int n = end - j0;
        if (n > 64) n = 64;
        int idx = (lane < n) ? csr_src[j0 + lane] : 0;   // coalesced
        int k = 0;
        for (; k + 8 <= n; k += 8) {
            int r0 = __shfl(idx, k + 0);
            int r1 = __shfl(idx, k + 1);
            int r2 = __shfl(idx, k + 2);
            int r3 = __shfl(idx, k + 3);
            int r4 = __shfl(idx, k + 4);
            int r5 = __shfl(idx, k + 5);
            int r6 = __shfl(idx, k + 6);
            int r7 = __shfl(idx, k + 7);
            unsigned int v0 = h2[(size_t)r0 * 64 + lane];
            unsigned int v1 = h2[(size_t)r1 * 64 + lane];
            unsigned int v2 = h2[(size_t)r2 * 64 + lane];
            unsigned int v3 = h2[(size_t)r3 * 64 + lane];
            unsigned int v4 = h2[(size_t)r4 * 64 + lane];
            unsigned int v5 = h2[(size_t)r5 * 64 + lane];
            unsigned int v6 = h2[(size_t)r6 * 64 + lane];
            unsigned int v7 = h2[(size_t)r7 * 64 + lane];
            ax += bf_lo(v0) + bf_lo(v1) + bf_lo(v2) + bf_lo(v3)
                + bf_lo(v4) + bf_lo(v5) + bf_lo(v6) + bf_lo(v7);
            ay += bf_hi(v0) + bf_hi(v1) + bf_hi(v2) + bf_hi(v3)
                + bf_hi(v4) + bf_hi(v5) + bf_hi(v6) + bf_hi(v7);
        }
        for (; k < n; k++) {
            int r = __shfl(idx, k);
            unsigned int v = h2[(size_t)r * 64 + lane];
            ax += bf_lo(v);
            ay += bf_hi(v);
        }
    }
    float dc = dinv[node];
    unsigned int vs = h2[(size_t)node * 64 + lane];   // h'[c] = dinv[c]*h[c]
    ax = dc * (ax + bf_lo(vs));
    ay = dc * (ay + bf_hi(vs));
    float2 bb = ((const float2*)b)[lane];
    float2 res = make_float2(ax + bb.x, ay + bb.y);
    ((float2*)out)[(size_t)node * 64 + lane] = res;
}

extern "C" void kernel_launch(void* const* d_in, const int* in_sizes, int n_in,
                              void* d_out, int out_size, void* d_ws, size_t ws_size,
                              hipStream_t stream) {
    const float* x  = (const float*)d_in[0];
    const float* W  = (const float*)d_in[1];
    const float* b  = (const float*)d_in[2];
    const int*   ei = (const int*)d_in[3];
    const int* row = ei;             // ei[0]
    const int* col = ei + N_EDGES;   // ei[1]

    char* ws = (char*)d_ws;
    __hip_bfloat16* h = (__hip_bfloat16*)(ws + 0);   // 2,560,000 B
    int*   deg      = (int*)  (ws + 2560000);
    float* dinv     = (float*)(ws + 2600192);
    int*   row_off  = (int*)  (ws + 2640384);
    int*   cursor   = (int*)  (ws + 2680576);
    int*   csr_src  = (int*)  (ws + 2720768);       // 2,560,000 B
    float* out      = (float*)d_out;

    hipLaunchKernelGGL(zero_deg_kernel, dim3((N_NODES + 255) / 256), dim3(256), 0, stream, deg);
    hipLaunchKernelGGL(count_deg_kernel, dim3(N_EDGES / 4 / 256), dim3(256), 0, stream, col, deg);
    hipLaunchKernelGGL(scan_kernel, dim3(1), dim3(1024), 0, stream, deg, row_off, cursor, dinv);
    hipLaunchKernelGGL(fill_csr_kernel, dim3(N_EDGES / 4 / 256), dim3(256), 0, stream, row, col, cursor, csr_src);
    hipLaunchKernelGGL(gemm_kernel, dim3((N_NODES + GM - 1) / GM), dim3(256), 0, stream, x, W, dinv, h);
    hipLaunchKernelGGL(gather_kernel, dim3((N_NODES + 3) / 4), dim3(256), 0, stream,
                       (const unsigned int*)h, dinv, row_off, csr_src, b, out);
}

// Round 5
// 133.523 us; speedup vs baseline: 1.8802x; 1.4759x over previous
//
#include <hip/hip_runtime.h>
#include <hip/hip_bf16.h>
#include <math.h>

#define N_NODES 10000
#define N_EDGES 640000
#define C 128          // IN_C == OUT_C
#define GM 32          // nodes per GEMM block
#define CHUNKS 128
#define EPC (N_EDGES / CHUNKS)   // 5000 edges per chunk

// ---------------- A: per-chunk LDS histogram -> u16 global ----------------
__global__ __launch_bounds__(256) void hist_kernel(const int* __restrict__ col,
                                                   unsigned short* __restrict__ hist) {
    __shared__ int lh[N_NODES];           // 40 KB
    int c = blockIdx.x;
    for (int i = threadIdx.x; i < N_NODES; i += 256) lh[i] = 0;
    __syncthreads();
    const int4* c4 = (const int4*)(col + c * EPC);
    for (int i = threadIdx.x; i < EPC / 4; i += 256) {
        int4 v = c4[i];
        atomicAdd(&lh[v.x], 1);
        atomicAdd(&lh[v.y], 1);
        atomicAdd(&lh[v.z], 1);
        atomicAdd(&lh[v.w], 1);
    }
    __syncthreads();
    // pack two counts per uint store (coalesced)
    unsigned int* hg = (unsigned int*)(hist + (size_t)c * N_NODES);
    for (int i = threadIdx.x; i < N_NODES / 2; i += 256) {
        unsigned int lo = (unsigned int)lh[2 * i];
        unsigned int hi = (unsigned int)lh[2 * i + 1];
        hg[i] = lo | (hi << 16);
    }
}

// ---------------- B: in-place exclusive prefix over chunks, per node ----------------
__global__ void chunk_prefix_kernel(unsigned short* __restrict__ hist,
                                    int* __restrict__ deg) {
    int n = blockIdx.x * blockDim.x + threadIdx.x;
    if (n >= N_NODES) return;
    int s = 0;
    for (int c = 0; c < CHUNKS; c += 8) {
        int t[8];
#pragma unroll
        for (int k = 0; k < 8; k++) t[k] = hist[(size_t)(c + k) * N_NODES + n];
#pragma unroll
        for (int k = 0; k < 8; k++) {
            hist[(size_t)(c + k) * N_NODES + n] = (unsigned short)s;
            s += t[k];
        }
    }
    deg[n] = s;
}

// ---------------- C: node prefix scan + dinv ----------------
__global__ __launch_bounds__(1024) void scan_kernel(const int* __restrict__ deg,
                                                    int* __restrict__ row_off,
                                                    float* __restrict__ dinv) {
    __shared__ int sm[1024];
    const int PER = 10;
    int tid = threadIdx.x;
    int base = tid * PER;
    int local[PER];
    int s = 0;
#pragma unroll
    for (int k = 0; k < PER; k++) {
        int i = base + k;
        int v = (i < N_NODES) ? deg[i] : 0;
        local[k] = s;
        s += v;
    }
    sm[tid] = s;
    __syncthreads();
    for (int off = 1; off < 1024; off <<= 1) {
        int t = (tid >= off) ? sm[tid - off] : 0;
        __syncthreads();
        sm[tid] += t;
        __syncthreads();
    }
    int excl_base = sm[tid] - s;
#pragma unroll
    for (int k = 0; k < PER; k++) {
        int i = base + k;
        if (i < N_NODES) row_off[i] = excl_base + local[k];
    }
    if (tid == 1023) row_off[N_NODES] = sm[1023];
    for (int i = tid; i < N_NODES; i += 1024) {
        dinv[i] = rsqrtf((float)(deg[i] + 1));
    }
}

// ---------------- D: scatter with LDS cursor (no global atomics) ----------------
__global__ __launch_bounds__(256) void scatter_kernel(const int* __restrict__ row,
                                                      const int* __restrict__ col,
                                                      const int* __restrict__ row_off,
                                                      const unsigned short* __restrict__ hist,
                                                      int* __restrict__ csr_src) {
    __shared__ int cur[N_NODES];          // 40 KB
    int c = blockIdx.x;
    const unsigned short* hb = hist + (size_t)c * N_NODES;
    for (int i = threadIdx.x; i < N_NODES; i += 256)
        cur[i] = row_off[i] + (int)hb[i];
    __syncthreads();
    const int4* c4 = (const int4*)(col + c * EPC);
    const int4* r4 = (const int4*)(row + c * EPC);
    for (int i = threadIdx.x; i < EPC / 4; i += 256) {
        int4 cv = c4[i];
        int4 rv = r4[i];
        csr_src[atomicAdd(&cur[cv.x], 1)] = rv.x;
        csr_src[atomicAdd(&cur[cv.y], 1)] = rv.y;
        csr_src[atomicAdd(&cur[cv.z], 1)] = rv.z;
        csr_src[atomicAdd(&cur[cv.w], 1)] = rv.w;
    }
}

// ---------------- h' = bf16(dinv * (x @ W^T)) ----------------
__global__ __launch_bounds__(256) void gemm_kernel(const float* __restrict__ x,
                                                   const float* __restrict__ W,
                                                   const float* __restrict__ dinv,
                                                   __hip_bfloat16* __restrict__ h) {
    __shared__ float4 xs[GM * 32];   // 32 nodes x 128 floats = 16 KB
    int block0 = blockIdx.x * GM;
    int tid = threadIdx.x;
    const float4* xv = (const float4*)x + (size_t)block0 * 32;
    int total4 = N_NODES * 32;
    for (int i = tid; i < GM * 32; i += 256) {
        int g = block0 * 32 + i;
        xs[i] = (g < total4) ? xv[i] : make_float4(0.f, 0.f, 0.f, 0.f);
    }
    __syncthreads();

    int ch = tid & 127;
    int ty = tid >> 7;
    const float4* Wv = (const float4*)(W + ch * C);
    float acc[GM / 2];
#pragma unroll
    for (int n = 0; n < GM / 2; n++) acc[n] = 0.f;

    for (int kk = 0; kk < 32; kk++) {
        float4 w4 = Wv[kk];
#pragma unroll
        for (int n = 0; n < GM / 2; n++) {
            float4 x4 = xs[(2 * n + ty) * 32 + kk];
            acc[n] += w4.x * x4.x + w4.y * x4.y + w4.z * x4.z + w4.w * x4.w;
        }
    }
#pragma unroll
    for (int n = 0; n < GM / 2; n++) {
        int node = block0 + 2 * n + ty;
        if (node < N_NODES)
            h[(size_t)node * C + ch] = __float2bfloat16(acc[n] * dinv[node]);
    }
}

// ---------------- gather: one wave per destination node ----------------
__device__ __forceinline__ float bf_lo(unsigned int v) {
    return __uint_as_float(v << 16);
}
__device__ __forceinline__ float bf_hi(unsigned int v) {
    return __uint_as_float(v & 0xffff0000u);
}

__global__ __launch_bounds__(256) void gather_kernel(const unsigned int* __restrict__ h2,
                                                     const float* __restrict__ dinv,
                                                     const int* __restrict__ row_off,
                                                     const int* __restrict__ csr_src,
                                                     const float* __restrict__ b,
                                                     float* __restrict__ out) {
    int wave = threadIdx.x >> 6;
    int lane = threadIdx.x & 63;
    int node = blockIdx.x * 4 + wave;
    if (node >= N_NODES) return;

    int beg = row_off[node];
    int end = row_off[node + 1];
    float ax = 0.f, ay = 0.f;

    for (int j0 = beg; j0 < end; j0 += 64) {
        int n = end - j0;
        if (n > 64) n = 64;
        int idx = (lane < n) ? csr_src[j0 + lane] : 0;   // coalesced
        int k = 0;
        for (; k + 8 <= n; k += 8) {
            int r0 = __shfl(idx, k + 0);
            int r1 = __shfl(idx, k + 1);
            int r2 = __shfl(idx, k + 2);
            int r3 = __shfl(idx, k + 3);
            int r4 = __shfl(idx, k + 4);
            int r5 = __shfl(idx, k + 5);
            int r6 = __shfl(idx, k + 6);
            int r7 = __shfl(idx, k + 7);
            unsigned int v0 = h2[(size_t)r0 * 64 + lane];
            unsigned int v1 = h2[(size_t)r1 * 64 + lane];
            unsigned int v2 = h2[(size_t)r2 * 64 + lane];
            unsigned int v3 = h2[(size_t)r3 * 64 + lane];
            unsigned int v4 = h2[(size_t)r4 * 64 + lane];
            unsigned int v5 = h2[(size_t)r5 * 64 + lane];
            unsigned int v6 = h2[(size_t)r6 * 64 + lane];
            unsigned int v7 = h2[(size_t)r7 * 64 + lane];
            ax += bf_lo(v0) + bf_lo(v1) + bf_lo(v2) + bf_lo(v3)
                + bf_lo(v4) + bf_lo(v5) + bf_lo(v6) + bf_lo(v7);
            ay += bf_hi(v0) + bf_hi(v1) + bf_hi(v2) + bf_hi(v3)
                + bf_hi(v4) + bf_hi(v5) + bf_hi(v6) + bf_hi(v7);
        }
        for (; k < n; k++) {
            int r = __shfl(idx, k);
            unsigned int v = h2[(size_t)r * 64 + lane];
            ax += bf_lo(v);
            ay += bf_hi(v);
        }
    }
    float dc = dinv[node];
    unsigned int vs = h2[(size_t)node * 64 + lane];
    ax = dc * (ax + bf_lo(vs));
    ay = dc * (ay + bf_hi(vs));
    float2 bb = ((const float2*)b)[lane];
    float2 res = make_float2(ax + bb.x, ay + bb.y);
    ((float2*)out)[(size_t)node * 64 + lane] = res;
}

extern "C" void kernel_launch(void* const* d_in, const int* in_sizes, int n_in,
                              void* d_out, int out_size, void* d_ws, size_t ws_size,
                              hipStream_t stream) {
    const float* x  = (const float*)d_in[0];
    const float* W  = (const float*)d_in[1];
    const float* b  = (const float*)d_in[2];
    const int*   ei = (const int*)d_in[3];
    const int* row = ei;             // ei[0]
    const int* col = ei + N_EDGES;   // ei[1]

    char* ws = (char*)d_ws;
    // footprint kept <= round-1-proven 7.84 MB
    __hip_bfloat16* h      = (__hip_bfloat16*)(ws + 0);       // 2,560,000 B
    unsigned short* hist   = (unsigned short*)(ws + 2560000); // 2,560,000 B (128 x 10000 u16)
    int*   deg      = (int*)  (ws + 5120000);                 //    40,000 B
    float* dinv     = (float*)(ws + 5160000);                 //    40,000 B
    int*   row_off  = (int*)  (ws + 5200000);                 //    40,004 B
    int*   csr_src  = (int*)  (ws + 5240016);                 // 2,560,000 B -> ends 7,800,016
    float* out      = (float*)d_out;

    hipLaunchKernelGGL(hist_kernel, dim3(CHUNKS), dim3(256), 0, stream, col, hist);
    hipLaunchKernelGGL(chunk_prefix_kernel, dim3((N_NODES + 255) / 256), dim3(256), 0, stream, hist, deg);
    hipLaunchKernelGGL(scan_kernel, dim3(1), dim3(1024), 0, stream, deg, row_off, dinv);
    hipLaunchKernelGGL(scatter_kernel, dim3(CHUNKS), dim3(256), 0, stream, row, col, row_off, hist, csr_src);
    hipLaunchKernelGGL(gemm_kernel, dim3((N_NODES + GM - 1) / GM), dim3(256), 0, stream, x, W, dinv, h);
    hipLaunchKernelGGL(gather_kernel, dim3((N_NODES + 3) / 4), dim3(256), 0, stream,
                       (const unsigned int*)h, dinv, row_off, csr_src, b, out);
}

// Round 6
// 117.569 us; speedup vs baseline: 2.1353x; 1.1357x over previous
//
#include <hip/hip_runtime.h>
#include <hip/hip_bf16.h>
#include <math.h>

#define N_NODES 10000
#define N_EDGES 640000
#define C 128          // IN_C == OUT_C
#define GM 32          // nodes per GEMM block
#define CHUNKS 128
#define EPC (N_EDGES / CHUNKS)   // 5000 edges per chunk

// ---------------- A: per-chunk LDS histogram -> u16 global ----------------
__global__ __launch_bounds__(256) void hist_kernel(const int* __restrict__ col,
                                                   unsigned short* __restrict__ hist) {
    __shared__ int lh[N_NODES];           // 40 KB
    int c = blockIdx.x;
    for (int i = threadIdx.x; i < N_NODES; i += 256) lh[i] = 0;
    __syncthreads();
    const int4* c4 = (const int4*)(col + c * EPC);
    for (int i = threadIdx.x; i < EPC / 4; i += 256) {
        int4 v = c4[i];
        atomicAdd(&lh[v.x], 1);
        atomicAdd(&lh[v.y], 1);
        atomicAdd(&lh[v.z], 1);
        atomicAdd(&lh[v.w], 1);
    }
    __syncthreads();
    unsigned int* hg = (unsigned int*)(hist + (size_t)c * N_NODES);
    for (int i = threadIdx.x; i < N_NODES / 2; i += 256) {
        unsigned int lo = (unsigned int)lh[2 * i];
        unsigned int hi = (unsigned int)lh[2 * i + 1];
        hg[i] = lo | (hi << 16);
    }
}

// ---------------- B: in-place exclusive prefix over chunks, per node ----------------
__global__ void chunk_prefix_kernel(unsigned short* __restrict__ hist,
                                    int* __restrict__ deg) {
    int n = blockIdx.x * blockDim.x + threadIdx.x;
    if (n >= N_NODES) return;
    int s = 0;
    for (int c = 0; c < CHUNKS; c += 8) {
        int t[8];
#pragma unroll
        for (int k = 0; k < 8; k++) t[k] = hist[(size_t)(c + k) * N_NODES + n];
#pragma unroll
        for (int k = 0; k < 8; k++) {
            hist[(size_t)(c + k) * N_NODES + n] = (unsigned short)s;
            s += t[k];
        }
    }
    deg[n] = s;
}

// ---------------- C: node prefix scan + dinv (shfl-based, 2 barriers) ----------------
__global__ __launch_bounds__(1024) void scan_kernel(const int* __restrict__ deg,
                                                    int* __restrict__ row_off,
                                                    float* __restrict__ dinv) {
    __shared__ int wsum[16];
    __shared__ int woff[17];
    const int PER = 10;
    int tid = threadIdx.x;
    int lane = tid & 63;
    int wid = tid >> 6;
    int base = tid * PER;
    int local[PER];
    int s = 0;
#pragma unroll
    for (int k = 0; k < PER; k++) {
        int i = base + k;
        int v = (i < N_NODES) ? deg[i] : 0;
        local[k] = s;
        s += v;
    }
    // inclusive wave scan of s
    int v = s;
#pragma unroll
    for (int off = 1; off < 64; off <<= 1) {
        int t = __shfl_up(v, off, 64);
        if (lane >= off) v += t;
    }
    if (lane == 63) wsum[wid] = v;
    __syncthreads();
    if (tid < 16) {
        int w = wsum[tid];
        int iv = w;
#pragma unroll
        for (int off = 1; off < 16; off <<= 1) {
            int t = __shfl_up(iv, off, 64);
            if (tid >= off) iv += t;
        }
        woff[tid] = iv - w;            // exclusive wave offset
        if (tid == 15) woff[16] = iv;  // grand total
    }
    __syncthreads();
    int excl_base = woff[wid] + (v - s);
#pragma unroll
    for (int k = 0; k < PER; k++) {
        int i = base + k;
        if (i < N_NODES) row_off[i] = excl_base + local[k];
    }
    if (tid == 0) row_off[N_NODES] = woff[16];
    for (int i = tid; i < N_NODES; i += 1024) {
        dinv[i] = rsqrtf((float)(deg[i] + 1));
    }
}

// ---------------- D+E fused: scatter (blocks 0..127) | gemm (blocks 128..440) ----
// Both depend only on scan outputs; fusing lets them co-schedule across CUs.
__global__ __launch_bounds__(256) void scatter_gemm_kernel(
        const int* __restrict__ row, const int* __restrict__ col,
        const int* __restrict__ row_off, const unsigned short* __restrict__ hist,
        int* __restrict__ csr_src,
        const float* __restrict__ x, const float* __restrict__ W,
        const float* __restrict__ dinv, __hip_bfloat16* __restrict__ h) {
    __shared__ __align__(16) int smem[N_NODES];   // 40 KB (gemm aliases 16 KB of it)
    int tid = threadIdx.x;
    if (blockIdx.x < CHUNKS) {
        // ---- scatter with LDS cursor (no global atomics) ----
        int c = blockIdx.x;
        const unsigned short* hb = hist + (size_t)c * N_NODES;
        for (int i = tid; i < N_NODES; i += 256)
            smem[i] = row_off[i] + (int)hb[i];
        __syncthreads();
        const int4* c4 = (const int4*)(col + c * EPC);
        const int4* r4 = (const int4*)(row + c * EPC);
        for (int i = tid; i < EPC / 4; i += 256) {
            int4 cv = c4[i];
            int4 rv = r4[i];
            csr_src[atomicAdd(&smem[cv.x], 1)] = rv.x;
            csr_src[atomicAdd(&smem[cv.y], 1)] = rv.y;
            csr_src[atomicAdd(&smem[cv.z], 1)] = rv.z;
            csr_src[atomicAdd(&smem[cv.w], 1)] = rv.w;
        }
    } else {
        // ---- h' = bf16(dinv * (x @ W^T)) ----
        float4* xs = (float4*)smem;   // 32 nodes x 32 float4 = 16 KB
        int block0 = (blockIdx.x - CHUNKS) * GM;
        const float4* xv = (const float4*)x + (size_t)block0 * 32;
        int total4 = N_NODES * 32;
        for (int i = tid; i < GM * 32; i += 256) {
            int g = block0 * 32 + i;
            xs[i] = (g < total4) ? xv[i] : make_float4(0.f, 0.f, 0.f, 0.f);
        }
        __syncthreads();

        int ch = tid & 127;
        int ty = tid >> 7;
        const float4* Wv = (const float4*)(W + ch * C);
        float acc[GM / 2];
#pragma unroll
        for (int n = 0; n < GM / 2; n++) acc[n] = 0.f;

        for (int kk = 0; kk < 32; kk++) {
            float4 w4 = Wv[kk];
#pragma unroll
            for (int n = 0; n < GM / 2; n++) {
                float4 x4 = xs[(2 * n + ty) * 32 + kk];
                acc[n] += w4.x * x4.x + w4.y * x4.y + w4.z * x4.z + w4.w * x4.w;
            }
        }
#pragma unroll
        for (int n = 0; n < GM / 2; n++) {
            int node = block0 + 2 * n + ty;
            if (node < N_NODES)
                h[(size_t)node * C + ch] = __float2bfloat16(acc[n] * dinv[node]);
        }
    }
}

// ---------------- gather: one wave per destination node ----------------
__device__ __forceinline__ float bf_lo(unsigned int v) {
    return __uint_as_float(v << 16);
}
__device__ __forceinline__ float bf_hi(unsigned int v) {
    return __uint_as_float(v & 0xffff0000u);
}

__global__ __launch_bounds__(256) void gather_kernel(const unsigned int* __restrict__ h2,
                                                     const float* __restrict__ dinv,
                                                     const int* __restrict__ row_off,
                                                     const int* __restrict__ csr_src,
                                                     const float* __restrict__ b,
                                                     float* __restrict__ out) {
    int wave = threadIdx.x >> 6;
    int lane = threadIdx.x & 63;
    int node = blockIdx.x * 4 + wave;
    if (node >= N_NODES) return;

    int beg = row_off[node];
    int end = row_off[node + 1];
    float ax = 0.f, ay = 0.f;

    for (int j0 = beg; j0 < end; j0 += 64) {
        int n = end - j0;
        if (n > 64) n = 64;
        int idx = (lane < n) ? csr_src[j0 + lane] : 0;   // coalesced
        int k = 0;
        for (; k + 8 <= n; k += 8) {
            int r0 = __shfl(idx, k + 0);
            int r1 = __shfl(idx, k + 1);
            int r2 = __shfl(idx, k + 2);
            int r3 = __shfl(idx, k + 3);
            int r4 = __shfl(idx, k + 4);
            int r5 = __shfl(idx, k + 5);
            int r6 = __shfl(idx, k + 6);
            int r7 = __shfl(idx, k + 7);
            unsigned int v0 = h2[(size_t)r0 * 64 + lane];
            unsigned int v1 = h2[(size_t)r1 * 64 + lane];
            unsigned int v2 = h2[(size_t)r2 * 64 + lane];
            unsigned int v3 = h2[(size_t)r3 * 64 + lane];
            unsigned int v4 = h2[(size_t)r4 * 64 + lane];
            unsigned int v5 = h2[(size_t)r5 * 64 + lane];
            unsigned int v6 = h2[(size_t)r6 * 64 + lane];
            unsigned int v7 = h2[(size_t)r7 * 64 + lane];
            ax += bf_lo(v0) + bf_lo(v1) + bf_lo(v2) + bf_lo(v3)
                + bf_lo(v4) + bf_lo(v5) + bf_lo(v6) + bf_lo(v7);
            ay += bf_hi(v0) + bf_hi(v1) + bf_hi(v2) + bf_hi(v3)
                + bf_hi(v4) + bf_hi(v5) + bf_hi(v6) + bf_hi(v7);
        }
        for (; k < n; k++) {
            int r = __shfl(idx, k);
            unsigned int v = h2[(size_t)r * 64 + lane];
            ax += bf_lo(v);
            ay += bf_hi(v);
        }
    }
    float dc = dinv[node];
    unsigned int vs = h2[(size_t)node * 64 + lane];
    ax = dc * (ax + bf_lo(vs));
    ay = dc * (ay + bf_hi(vs));
    float2 bb = ((const float2*)b)[lane];
    float2 res = make_float2(ax + bb.x, ay + bb.y);
    ((float2*)out)[(size_t)node * 64 + lane] = res;
}

extern "C" void kernel_launch(void* const* d_in, const int* in_sizes, int n_in,
                              void* d_out, int out_size, void* d_ws, size_t ws_size,
                              hipStream_t stream) {
    const float* x  = (const float*)d_in[0];
    const float* W  = (const float*)d_in[1];
    const float* b  = (const float*)d_in[2];
    const int*   ei = (const int*)d_in[3];
    const int* row = ei;             // ei[0]
    const int* col = ei + N_EDGES;   // ei[1]

    char* ws = (char*)d_ws;
    __hip_bfloat16* h      = (__hip_bfloat16*)(ws + 0);       // 2,560,000 B
    unsigned short* hist   = (unsigned short*)(ws + 2560000); // 2,560,000 B
    int*   deg      = (int*)  (ws + 5120000);                 //    40,000 B
    float* dinv     = (float*)(ws + 5160000);                 //    40,000 B
    int*   row_off  = (int*)  (ws + 5200000);                 //    40,004 B
    int*   csr_src  = (int*)  (ws + 5240016);                 // 2,560,000 B
    float* out      = (float*)d_out;

    hipLaunchKernelGGL(hist_kernel, dim3(CHUNKS), dim3(256), 0, stream, col, hist);
    hipLaunchKernelGGL(chunk_prefix_kernel, dim3((N_NODES + 255) / 256), dim3(256), 0, stream, hist, deg);
    hipLaunchKernelGGL(scan_kernel, dim3(1), dim3(1024), 0, stream, deg, row_off, dinv);
    hipLaunchKernelGGL(scatter_gemm_kernel, dim3(CHUNKS + (N_NODES + GM - 1) / GM), dim3(256), 0, stream,
                       row, col, row_off, hist, csr_src, x, W, dinv, h);
    hipLaunchKernelGGL(gather_kernel, dim3((N_NODES + 3) / 4), dim3(256), 0, stream,
                       (const unsigned int*)h, dinv, row_off, csr_src, b, out);
}